// Round 6
// baseline (309.436 us; speedup 1.0000x reference)
//
#include <hip/hip_runtime.h>
#include <stdint.h>

#define K_DIM 1024
#define N_DIM 1024
#define NKT 16             // K / 64 k-tiles
#define WTILE 8192         // wq tile: 128 n-rows x 64 k int8
#define LDA 80             // fused-fallback LDS stride

typedef int v4i __attribute__((ext_vector_type(4)));

__device__ __forceinline__ int quant1(float f, float inv) {
    return (int)fminf(fmaxf(rintf(f * inv), -128.f), 127.f);
}
__device__ __forceinline__ uint32_t pack4(int a, int b, int c, int d) {
    return (uint32_t)(a & 255) | ((uint32_t)(b & 255) << 8) |
           ((uint32_t)(c & 255) << 16) | ((uint32_t)(d & 255) << 24);
}
// Swizzled byte offset inside a [rows][64] int8 tile: XOR bits 4-6 with (r&7).
// Bijective, 16B-alignment preserved; fragment reads (16 lanes, stride 64B,
// fixed 16B col) spread across all 8 four-bank groups. Proven in R3.
__device__ __forceinline__ int swz(int r, int c) {
    return (r * 64 + c) ^ ((r & 7) << 4);
}
__device__ __forceinline__ bool probe_x_is_f32(const void* xptr) {
    // even halfwords: bf16/f16-origin data decodes mostly into [2^-3, 2);
    // f32-widened x has lo halfwords = mantissa<<13, ~none in range.
    const uint16_t* xu = (const uint16_t*)xptr;
    int lane = (int)(threadIdx.x & 63);
    float pv = __uint_as_float(((uint32_t)xu[2 * lane]) << 16);
    float pa = fabsf(pv);
    unsigned long long mx = __ballot(pa >= 0.125f && pa < 2.0f);
    return (__popcll(mx) < 32);
}

// ================= weight pre-pack: int32 -> int8, swizzled tiles ===========
// tile t = nblk*16 + kb (8 KB each), proven R3 layout.
__global__ __launch_bounds__(256) void prep_w_kernel(
    const int* __restrict__ w32, uint8_t* __restrict__ wq)
{
    int c = blockIdx.x * 256 + threadIdx.x;   // [0, 65536) 16-elem chunks
    int q = c & 3;
    int r = (c >> 2) & 127;
    int t = c >> 9;                           // nblk*16 + kb
    size_t row = (size_t)(t >> 4) * 128 + r;
    int    col = (t & 15) * 64 + q * 16;
    const int4* src = (const int4*)(w32 + row * K_DIM + col);
    uint32_t pk[4];
#pragma unroll
    for (int g = 0; g < 4; g++) {
        int4 v = src[g];
        pk[g] = pack4(v.x, v.y, v.z, v.w);
    }
    *(uint4*)(wq + ((size_t)t << 13) + swz(r, q * 16)) =
        make_uint4(pk[0], pk[1], pk[2], pk[3]);
}

// ================= fused quant + GEMM =======================================
// Block owns x rows [mblk*64, +64): quantizes them ONCE into a 64KB LDS panel
// (progressively, overlapped with n-pass 0's MFMAs), then n-passes 1..7 reuse
// the panel barrier-free. wq is L2-resident. x traffic: exactly once.
template<bool X_F32>
__device__ __forceinline__ void fused_body(
    uint8_t (*lA)[4096],                       // [NKT][64 rows x 64B], swizzled
    const void* __restrict__ xptr,
    const uint8_t* __restrict__ wq,
    const float* __restrict__ wscale,
    const float s,
    const float* __restrict__ bias,
    float* __restrict__ out)
{
    const int tid  = threadIdx.x;
    const int lane = tid & 63;
    const int wave = tid >> 6;
    const int wm   = wave >> 1;          // 0..1 : 32-row band
    const int wn   = wave & 1;           // 0..1 : 64-col band
    const int quad = lane >> 4;
    const int l16  = lane & 15;

    const int mblk = (int)blockIdx.x;
    const int m0   = mblk * 64;
    const float inv = 1.0f / s;

    // quant mapping: thread -> (row qr, 16B col chunk qc) of each k-tile
    const int qr = tid >> 2;             // 0..63
    const int qc = (tid & 3) * 16;       // 0,16,32,48
    const int wdst = swz(qr, qc);        // LDS byte offset within tile

    const float*    xbf = (const float*)xptr    + (size_t)(m0 + qr) * K_DIM + qc;
    const uint16_t* xbh = (const uint16_t*)xptr + (size_t)(m0 + qr) * K_DIM + qc;

    int offA[2], offB[4];
#pragma unroll
    for (int mt = 0; mt < 2; mt++) offA[mt] = swz(wm * 32 + mt * 16 + l16, quad * 16);
#pragma unroll
    for (int nt = 0; nt < 4; nt++) offB[nt] = swz(wn * 64 + nt * 16 + l16, quad * 16);

    // ---- prologue: quantize k-tiles 0..3 into LDS ----
#pragma unroll
    for (int kt = 0; kt < 4; kt++) {
        uint32_t pk[4];
        if (X_F32) {
            const float4* s4 = (const float4*)(xbf + kt * 64);
            float4 a = s4[0], b = s4[1], c = s4[2], d = s4[3];
            pk[0] = pack4(quant1(a.x,inv),quant1(a.y,inv),quant1(a.z,inv),quant1(a.w,inv));
            pk[1] = pack4(quant1(b.x,inv),quant1(b.y,inv),quant1(b.z,inv),quant1(b.w,inv));
            pk[2] = pack4(quant1(c.x,inv),quant1(c.y,inv),quant1(c.z,inv),quant1(c.w,inv));
            pk[3] = pack4(quant1(d.x,inv),quant1(d.y,inv),quant1(d.z,inv),quant1(d.w,inv));
        } else {
            const uint4* s4 = (const uint4*)(xbh + kt * 64);
            union { uint4 v[2]; uint32_t u[8]; } ax;
            ax.v[0] = s4[0]; ax.v[1] = s4[1];
#pragma unroll
            for (int i = 0; i < 4; i++) {
                uint32_t wa = ax.u[2*i], wb = ax.u[2*i+1];
                pk[i] = pack4(quant1(__uint_as_float(wa << 16), inv),
                              quant1(__uint_as_float(wa & 0xffff0000u), inv),
                              quant1(__uint_as_float(wb << 16), inv),
                              quant1(__uint_as_float(wb & 0xffff0000u), inv));
            }
        }
        *(uint4*)&lA[kt][wdst] = make_uint4(pk[0], pk[1], pk[2], pk[3]);
    }
    __syncthreads();

    // ---- n-pass 0: compute + progressive quant of k-tiles 4..15 ----
    {
        v4i acc[2][4] = {};
#pragma unroll
        for (int kb = 0; kb < NKT; kb++) {
            // issue next-quant x-loads EARLY (consumed after the MFMAs)
            float4 rf0, rf1, rf2, rf3; uint4 rh0, rh1;
            if (kb < NKT - 4) {
                if (X_F32) {
                    const float4* s4 = (const float4*)(xbf + (kb + 4) * 64);
                    rf0 = s4[0]; rf1 = s4[1]; rf2 = s4[2]; rf3 = s4[3];
                } else {
                    const uint4* s4 = (const uint4*)(xbh + (kb + 4) * 64);
                    rh0 = s4[0]; rh1 = s4[1];
                }
            }
            v4i af[2], bf[4];
            af[0] = *(const v4i*)&lA[kb][offA[0]];
            af[1] = *(const v4i*)&lA[kb][offA[1]];
            const uint8_t* wt = wq + (size_t)kb * WTILE;    // np = 0
#pragma unroll
            for (int nt = 0; nt < 4; nt++)
                bf[nt] = *(const v4i*)(wt + offB[nt]);
#pragma unroll
            for (int mt = 0; mt < 2; mt++)
#pragma unroll
                for (int nt = 0; nt < 4; nt++)
                    acc[mt][nt] = __builtin_amdgcn_mfma_i32_16x16x64_i8(
                        af[mt], bf[nt], acc[mt][nt], 0, 0, 0);
            // quant LATE, write tile kb+4 (read 4 iters / >=1 barrier later)
            if (kb < NKT - 4) {
                uint32_t pk[4];
                if (X_F32) {
                    pk[0] = pack4(quant1(rf0.x,inv),quant1(rf0.y,inv),quant1(rf0.z,inv),quant1(rf0.w,inv));
                    pk[1] = pack4(quant1(rf1.x,inv),quant1(rf1.y,inv),quant1(rf1.z,inv),quant1(rf1.w,inv));
                    pk[2] = pack4(quant1(rf2.x,inv),quant1(rf2.y,inv),quant1(rf2.z,inv),quant1(rf2.w,inv));
                    pk[3] = pack4(quant1(rf3.x,inv),quant1(rf3.y,inv),quant1(rf3.z,inv),quant1(rf3.w,inv));
                } else {
                    uint32_t u[4] = { rh0.x, rh0.y, rh0.z, rh0.w };
                    uint32_t v[4] = { rh1.x, rh1.y, rh1.z, rh1.w };
#pragma unroll
                    for (int i = 0; i < 2; i++) {
                        uint32_t wa = u[2*i], wb = u[2*i+1];
                        pk[i] = pack4(quant1(__uint_as_float(wa << 16), inv),
                                      quant1(__uint_as_float(wa & 0xffff0000u), inv),
                                      quant1(__uint_as_float(wb << 16), inv),
                                      quant1(__uint_as_float(wb & 0xffff0000u), inv));
                    }
#pragma unroll
                    for (int i = 0; i < 2; i++) {
                        uint32_t wa = v[2*i], wb = v[2*i+1];
                        pk[2+i] = pack4(quant1(__uint_as_float(wa << 16), inv),
                                        quant1(__uint_as_float(wa & 0xffff0000u), inv),
                                        quant1(__uint_as_float(wb << 16), inv),
                                        quant1(__uint_as_float(wb & 0xffff0000u), inv));
                    }
                }
                *(uint4*)&lA[kb + 4][wdst] = make_uint4(pk[0], pk[1], pk[2], pk[3]);
            }
            __syncthreads();
        }
        // epilogue np=0
        float osc[4], obi[4];
#pragma unroll
        for (int nt = 0; nt < 4; nt++) {
            int col = wn * 64 + nt * 16 + l16;
            osc[nt] = s * wscale[col];
            obi[nt] = bias[col];
        }
#pragma unroll
        for (int mt = 0; mt < 2; mt++) {
            int rowb = m0 + wm * 32 + mt * 16 + quad * 4;
#pragma unroll
            for (int nt = 0; nt < 4; nt++) {
                int col = wn * 64 + nt * 16 + l16;
#pragma unroll
                for (int r = 0; r < 4; r++)
                    out[(size_t)(rowb + r) * N_DIM + col] =
                        (float)acc[mt][nt][r] * osc[nt] + obi[nt];
            }
        }
    }

    // ---- n-passes 1..7: barrier-free, panel reused from LDS ----
    for (int np = 1; np < 8; np++) {
        const uint8_t* wbase = wq + (size_t)np * (NKT * WTILE);
        v4i acc[2][4] = {};
#pragma unroll
        for (int kb = 0; kb < NKT; kb++) {
            v4i af[2], bf[4];
            af[0] = *(const v4i*)&lA[kb][offA[0]];
            af[1] = *(const v4i*)&lA[kb][offA[1]];
            const uint8_t* wt = wbase + (size_t)kb * WTILE;
#pragma unroll
            for (int nt = 0; nt < 4; nt++)
                bf[nt] = *(const v4i*)(wt + offB[nt]);
#pragma unroll
            for (int mt = 0; mt < 2; mt++)
#pragma unroll
                for (int nt = 0; nt < 4; nt++)
                    acc[mt][nt] = __builtin_amdgcn_mfma_i32_16x16x64_i8(
                        af[mt], bf[nt], acc[mt][nt], 0, 0, 0);
        }
        const int n0 = np * 128;
        float osc[4], obi[4];
#pragma unroll
        for (int nt = 0; nt < 4; nt++) {
            int col = n0 + wn * 64 + nt * 16 + l16;
            osc[nt] = s * wscale[col];
            obi[nt] = bias[col];
        }
#pragma unroll
        for (int mt = 0; mt < 2; mt++) {
            int rowb = m0 + wm * 32 + mt * 16 + quad * 4;
#pragma unroll
            for (int nt = 0; nt < 4; nt++) {
                int col = n0 + wn * 64 + nt * 16 + l16;
#pragma unroll
                for (int r = 0; r < 4; r++)
                    out[(size_t)(rowb + r) * N_DIM + col] =
                        (float)acc[mt][nt][r] * osc[nt] + obi[nt];
            }
        }
    }
}

__global__ __launch_bounds__(256, 2) void fused_gemm_kernel(
    const void* __restrict__ xptr,
    const uint8_t* __restrict__ wq,
    const float* __restrict__ wscale,
    const float* __restrict__ ascale_p,
    const float* __restrict__ bias,
    float* __restrict__ out)
{
    __shared__ uint8_t lA[NKT][4096];    // 64 KB -> 2 blocks/CU
    const bool x_is_f32 = probe_x_is_f32(xptr);
    const float s = ascale_p[0];
    if (x_is_f32) fused_body<true >(lA, xptr, wq, wscale, s, bias, out);
    else          fused_body<false>(lA, xptr, wq, wscale, s, bias, out);
}

// ================= fallback: proven fused kernel (R0, 655 us) ===============
template<bool X_F32>
__device__ __forceinline__ void gemm_body(
    int8_t* lA, int8_t* lB,
    const void* __restrict__ xptr,
    const int* __restrict__ w32,
    const float* __restrict__ wscale,
    const float s,
    const float* __restrict__ bias,
    float* __restrict__ out)
{
    const int tid  = threadIdx.x;
    const int lane = tid & 63;
    const int wave = tid >> 6;
    const int wm   = wave >> 1;
    const int wn   = wave & 1;
    const int quad = lane >> 4;
    const int l16  = lane & 15;

    const int mblk = (int)blockIdx.x >> 3;
    const int nblk = (int)blockIdx.x & 7;
    const int m0 = mblk * 128;
    const int n0 = nblk * 128;

    const float inv = 1.0f / s;
    const int ar = tid >> 1;
    const int ah = (tid & 1) * 32;

    const float*    xrowf = (const float*)xptr    + (size_t)(m0 + ar) * K_DIM + ah;
    const uint16_t* xrowh = (const uint16_t*)xptr + (size_t)(m0 + ar) * K_DIM + ah;
    const int*      wrow  = w32 + (size_t)(n0 + ar) * K_DIM + ah;

    v4i acc[4][4] = {};

    for (int kb = 0; kb < K_DIM; kb += 64) {
        {
            uint32_t pk[8];
            if (X_F32) {
                const float4* xs = (const float4*)(xrowf + kb);
#pragma unroll
                for (int g = 0; g < 8; g++) {
                    float4 v = xs[g];
                    pk[g] = pack4(quant1(v.x, inv), quant1(v.y, inv),
                                  quant1(v.z, inv), quant1(v.w, inv));
                }
            } else {
                const uint4* xs = (const uint4*)(xrowh + kb);
                union { uint4 v[4]; uint32_t u[16]; } ax;
                ax.v[0] = xs[0]; ax.v[1] = xs[1]; ax.v[2] = xs[2]; ax.v[3] = xs[3];
#pragma unroll
                for (int i = 0; i < 8; i++) {
                    uint32_t wa = ax.u[2 * i], wb = ax.u[2 * i + 1];
                    pk[i] = pack4(quant1(__uint_as_float(wa << 16), inv),
                                  quant1(__uint_as_float(wa & 0xffff0000u), inv),
                                  quant1(__uint_as_float(wb << 16), inv),
                                  quant1(__uint_as_float(wb & 0xffff0000u), inv));
                }
            }
            uint4* adst = (uint4*)&lA[ar * LDA + ah];
            adst[0] = make_uint4(pk[0], pk[1], pk[2], pk[3]);
            adst[1] = make_uint4(pk[4], pk[5], pk[6], pk[7]);
        }
        {
            const int4* ws4 = (const int4*)(wrow + kb);
            uint32_t pb[8];
#pragma unroll
            for (int g = 0; g < 8; g++) {
                int4 v = ws4[g];
                pb[g] = pack4(v.x, v.y, v.z, v.w);
            }
            uint4* bdst = (uint4*)&lB[ar * LDA + ah];
            bdst[0] = make_uint4(pb[0], pb[1], pb[2], pb[3]);
            bdst[1] = make_uint4(pb[4], pb[5], pb[6], pb[7]);
        }
        __syncthreads();

        v4i af[4], bf[4];
#pragma unroll
        for (int mt = 0; mt < 4; mt++)
            af[mt] = *(const v4i*)&lA[(wm * 64 + mt * 16 + l16) * LDA + quad * 16];
#pragma unroll
        for (int nt = 0; nt < 4; nt++)
            bf[nt] = *(const v4i*)&lB[(wn * 64 + nt * 16 + l16) * LDA + quad * 16];
#pragma unroll
        for (int mt = 0; mt < 4; mt++)
#pragma unroll
            for (int nt = 0; nt < 4; nt++)
                acc[mt][nt] = __builtin_amdgcn_mfma_i32_16x16x64_i8(af[mt], bf[nt], acc[mt][nt], 0, 0, 0);
        __syncthreads();
    }

    float osc[4], obi[4];
#pragma unroll
    for (int nt = 0; nt < 4; nt++) {
        int col = n0 + wn * 64 + nt * 16 + l16;
        osc[nt] = s * wscale[col];
        obi[nt] = bias[col];
    }
#pragma unroll
    for (int mt = 0; mt < 4; mt++) {
        int rowb = m0 + wm * 64 + mt * 16 + quad * 4;
#pragma unroll
        for (int nt = 0; nt < 4; nt++) {
            int col = n0 + wn * 64 + nt * 16 + l16;
#pragma unroll
            for (int r = 0; r < 4; r++) {
                out[(size_t)(rowb + r) * N_DIM + col] =
                    (float)acc[mt][nt][r] * osc[nt] + obi[nt];
            }
        }
    }
}

__global__ __launch_bounds__(256, 2) void int8_linear_fused(
    const void* __restrict__ xptr,
    const int* __restrict__ w32,
    const float* __restrict__ wscale,
    const float* __restrict__ ascale_p,
    const float* __restrict__ bias,
    float* __restrict__ out)
{
    __shared__ int8_t lA[128 * LDA];
    __shared__ int8_t lB[128 * LDA];
    const bool x_is_f32 = probe_x_is_f32(xptr);
    const float s = ascale_p[0];
    if (x_is_f32) gemm_body<true >(lA, lB, xptr, w32, wscale, s, bias, out);
    else          gemm_body<false>(lA, lB, xptr, w32, wscale, s, bias, out);
}

// ================= launch ===================================================
extern "C" void kernel_launch(void* const* d_in, const int* in_sizes, int n_in,
                              void* d_out, int out_size, void* d_ws, size_t ws_size,
                              hipStream_t stream) {
    const void*  xptr   = d_in[0];              // f16 widened to f32 by harness
    const int*   w32    = (const int*)d_in[1];  // int8 widened to int32
    const float* wscale = (const float*)d_in[2];
    const float* ascale = (const float*)d_in[3];
    const float* bias   = (const float*)d_in[4];
    float*       out    = (float*)d_out;        // f16 output -> float*

    int M = in_sizes[0] / K_DIM;                // 32768
    size_t need = (size_t)N_DIM * K_DIM;        // wq only: 1 MB

    bool split_ok = (d_ws != nullptr) && (ws_size >= need) && (M == 32768);

    if (split_ok) {
        uint8_t* wq = (uint8_t*)d_ws;
        prep_w_kernel<<<dim3(256), 256, 0, stream>>>(w32, wq);
        fused_gemm_kernel<<<dim3(M / 64), 256, 0, stream>>>(
            xptr, wq, wscale, ascale, bias, out);
    } else {
        dim3 grid((M / 128) * (N_DIM / 128));
        int8_linear_fused<<<grid, 256, 0, stream>>>(
            xptr, w32, wscale, ascale, bias, out);
    }
}